// Round 1
// baseline (420.415 us; speedup 1.0000x reference)
//
#include <hip/hip_runtime.h>
#include <math.h>

#define HSZ   4096
#define RROWS 16            // k-rows per slab (block reads RROWS full rows = 256 KB contiguous)
#define NSLAB 256           // HSZ / RROWS

struct WPtrs { const float* W[8]; };
struct BPtrs { const float* b[8]; };

__device__ __forceinline__ void fma4(float4& a, float s, float4 w) {
    a.x = fmaf(s, w.x, a.x);
    a.y = fmaf(s, w.y, a.y);
    a.z = fmaf(s, w.z, a.z);
    a.w = fmaf(s, w.w, a.w);
}

// --- stage 1: per-slab partial GEMV --------------------------------------
// Block (mat, slab) reads rows [slab*16, slab*16+16) of W[mat] — a fully
// contiguous 256 KB stream. x-side (mat<4) writes partials px[slab][mat][j]
// unconditionally (no atomics). h-side (mat>=4) early-exits on an all-zero
// h chunk, otherwise atomically accumulates into hg (only pays when h!=0).
__global__ __launch_bounds__(256, 8) void lstm_gemv_kernel(
        WPtrs wp, const float* __restrict__ x, const float* __restrict__ hv,
        float* __restrict__ px, float* __restrict__ hg) {
    const int mat  = blockIdx.x >> 8;            // 0..7
    const int slab = blockIdx.x & (NSLAB - 1);   // 0..255
    const int tid  = threadIdx.x;
    const float* __restrict__ v = (mat < 4) ? x : hv;

    __shared__ float vs[RROWS];
    __shared__ int nz;
    if (tid == 0) nz = 0;
    __syncthreads();
    if (tid < 64) {                              // wave 0 only
        float val = (tid < RROWS) ? v[slab * RROWS + tid] : 0.0f;
        if (tid < RROWS) vs[tid] = val;
        if (__any(val != 0.0f) && tid == 0) nz = 1;
    }
    __syncthreads();
    if (mat >= 4 && !nz) return;                 // zero h chunk -> skip weights

    const float* __restrict__ Wb = wp.W[mat] + (size_t)slab * RROWS * HSZ;
    const int c0 = tid * 4;                      // quarter-row offsets: +0,+1024,+2048,+3072
    float4 a0 = make_float4(0.f, 0.f, 0.f, 0.f), a1 = a0, a2 = a0, a3 = a0;
#pragma unroll
    for (int k = 0; k < RROWS; k += 2) {
        const float* r0 = Wb + (size_t)k * HSZ + c0;
        const float* r1 = r0 + HSZ;
        float4 w00 = *(const float4*)(r0);
        float4 w01 = *(const float4*)(r0 + 1024);
        float4 w02 = *(const float4*)(r0 + 2048);
        float4 w03 = *(const float4*)(r0 + 3072);
        float4 w10 = *(const float4*)(r1);
        float4 w11 = *(const float4*)(r1 + 1024);
        float4 w12 = *(const float4*)(r1 + 2048);
        float4 w13 = *(const float4*)(r1 + 3072);
        float x0 = vs[k], x1 = vs[k + 1];
        fma4(a0, x0, w00); fma4(a1, x0, w01); fma4(a2, x0, w02); fma4(a3, x0, w03);
        fma4(a0, x1, w10); fma4(a1, x1, w11); fma4(a2, x1, w12); fma4(a3, x1, w13);
    }
    if (mat < 4) {
        float* dst = px + ((size_t)slab * 4 + mat) * HSZ + c0;
        *(float4*)(dst)        = a0;
        *(float4*)(dst + 1024) = a1;
        *(float4*)(dst + 2048) = a2;
        *(float4*)(dst + 3072) = a3;
    } else {
        float* dst = hg + (size_t)(mat - 4) * HSZ + c0;
        atomicAdd(dst + 0,    a0.x); atomicAdd(dst + 1,    a0.y);
        atomicAdd(dst + 2,    a0.z); atomicAdd(dst + 3,    a0.w);
        atomicAdd(dst + 1024, a1.x); atomicAdd(dst + 1025, a1.y);
        atomicAdd(dst + 1026, a1.z); atomicAdd(dst + 1027, a1.w);
        atomicAdd(dst + 2048, a2.x); atomicAdd(dst + 2049, a2.y);
        atomicAdd(dst + 2050, a2.z); atomicAdd(dst + 2051, a2.w);
        atomicAdd(dst + 3072, a3.x); atomicAdd(dst + 3073, a3.y);
        atomicAdd(dst + 3074, a3.z); atomicAdd(dst + 3075, a3.w);
    }
}

// --- stage 2: fold 256 slab-partials + h contribution + biases into gates ---
// Block b: gate m = b&3, 64-wide j tile jt = b>>2. Threads: (j_local, slab-group).
__global__ __launch_bounds__(256) void lstm_reduce_kernel(
        const float* __restrict__ px, const float* __restrict__ hg,
        BPtrs bp, float* __restrict__ gates) {
    const int m  = blockIdx.x & 3;
    const int j0 = (blockIdx.x >> 2) << 6;       // 0..4032 step 64
    const int jl = threadIdx.x & 63;
    const int sg = threadIdx.x >> 6;             // 0..3 (64 slabs each)
    const float* p = px + ((size_t)(sg * 64) * 4 + m) * HSZ + j0 + jl;
    float s0 = 0.f, s1 = 0.f, s2 = 0.f, s3 = 0.f;
#pragma unroll
    for (int i = 0; i < 64; i += 4) {
        s0 += p[(size_t)(i + 0) * 4 * HSZ];
        s1 += p[(size_t)(i + 1) * 4 * HSZ];
        s2 += p[(size_t)(i + 2) * 4 * HSZ];
        s3 += p[(size_t)(i + 3) * 4 * HSZ];
    }
    __shared__ float red[4][64];
    red[sg][jl] = (s0 + s1) + (s2 + s3);
    __syncthreads();
    if (threadIdx.x < 64) {
        int j = j0 + threadIdx.x;
        float t = red[0][threadIdx.x] + red[1][threadIdx.x]
                + red[2][threadIdx.x] + red[3][threadIdx.x];
        t += hg[m * HSZ + j] + bp.b[m][j] + bp.b[m + 4][j];
        gates[m * HSZ + j] = t;
    }
}

// --- stage 3: activations + cell update -------------------------------------
__device__ __forceinline__ float sigmoidf_fast(float v) {
    return 1.0f / (1.0f + __expf(-v));
}

__global__ void lstm_final_kernel(const float* __restrict__ gates,
                                  const float* __restrict__ c,
                                  float* __restrict__ out) {
    int j = blockIdx.x * 256 + threadIdx.x;      // [0, 4096)
    float ig = gates[j];
    float fg = gates[HSZ + j];
    float gg = gates[2 * HSZ + j];
    float og = gates[3 * HSZ + j];
    float it = sigmoidf_fast(ig);
    float ft = sigmoidf_fast(fg);
    float gt = tanhf(gg);
    float ot = sigmoidf_fast(og);
    float cn = ft * c[j] + it * gt;
    out[j] = ot * tanhf(cn);
}

extern "C" void kernel_launch(void* const* d_in, const int* in_sizes, int n_in,
                              void* d_out, int out_size, void* d_ws, size_t ws_size,
                              hipStream_t stream) {
    const float* x = (const float*)d_in[0];
    WPtrs wp;
    for (int i = 0; i < 8; ++i) wp.W[i] = (const float*)d_in[1 + i];   // Wii..Who
    BPtrs bp;
    for (int i = 0; i < 8; ++i) bp.b[i] = (const float*)d_in[9 + i];   // bii..bho
    const float* h = (const float*)d_in[17];
    const float* c = (const float*)d_in[18];

    float* px    = (float*)d_ws;                  // [256][4][4096] = 16 MB partials
    float* hg    = px + (size_t)NSLAB * 4 * HSZ;  // [4][4096] h-side accumulators
    float* gates = hg + 4 * HSZ;                  // [4][4096] reduced gates

    hipMemsetAsync(hg, 0, 4 * HSZ * sizeof(float), stream);
    lstm_gemv_kernel<<<8 * NSLAB, 256, 0, stream>>>(wp, x, h, px, hg);
    lstm_reduce_kernel<<<NSLAB, 256, 0, stream>>>(px, hg, bp, gates);
    lstm_final_kernel<<<HSZ / 256, 256, 0, stream>>>(gates, c, (float*)d_out);
}